// Round 5
// baseline (287.295 us; speedup 1.0000x reference)
//
#include <hip/hip_runtime.h>
#include <hip/hip_bf16.h>
#include <stdint.h>

typedef unsigned short ushort_t;
typedef __attribute__((ext_vector_type(8))) short short8;
typedef __attribute__((ext_vector_type(4))) float floatx4;

// ---------- helpers ----------
__device__ __forceinline__ ushort_t f2bf(float f) {
    union { float f; unsigned u; } v; v.f = f;
    unsigned r = v.u + 0x7fffu + ((v.u >> 16) & 1u);   // RTNE
    return (ushort_t)(r >> 16);
}

__device__ __forceinline__ void async16(ushort_t* lds, const ushort_t* g) {
    __builtin_amdgcn_global_load_lds(
        (const __attribute__((address_space(1))) unsigned int*)g,
        (__attribute__((address_space(3))) unsigned int*)lds, 16, 0, 0);
}

// ================= the reshape trap (load-bearing comment) =================
// Reference: w3 axes (i0,i1,o0,o1), flat = ii*4096+oo, then reshape(4096,1024):
//   W_mat[r][c]: ii = r>>2, oo = (r&3)*1024 + c   (c is x's column!)
// out[s][r] = sum_k A2[r>>2][k] * Z[s][(r&3)*256+k]
//   Z[s][b*256+k] = sum_c x[s][c] * B2[k][b*1024+c]   (V below = that B-slice)
// A2[ii][k]=sum_r1 c0*c1 (k=r0*16+r2);  B2[k][oo]=sum_r3 c2*c3.
// ===========================================================================

// ---------- prep: cvt x->bf16; V[k'][c]; A2b[a][k] (all bf16) ----------
// blocks [0,8192): cvt; [8192,12288): V (1024x1024); [12288,13312): A2b (1024x256)
__global__ __launch_bounds__(256) void prep_all(const float* __restrict__ x,
                                                const float* __restrict__ c0,
                                                const float* __restrict__ c1,
                                                const float* __restrict__ c2,
                                                const float* __restrict__ c3,
                                                ushort_t* __restrict__ Xb,
                                                ushort_t* __restrict__ V,
                                                ushort_t* __restrict__ A2b) {
    const int blk = blockIdx.x, t = threadIdx.x;
    if (blk < 8192) {
        int i = blk * 256 + t;                 // float4 index, n4 = 2M
        float4 v = ((const float4*)x)[i];
        ushort4 r;
        r.x = f2bf(v.x); r.y = f2bf(v.y); r.z = f2bf(v.z); r.w = f2bf(v.w);
        ((ushort4*)Xb)[i] = r;
    } else if (blk < 12288) {
        int id = (blk - 8192) * 256 + t;       // [0, 1024*1024)
        int c = id & 1023, kp = id >> 10;      // kp = b*256+k
        int b = kp >> 8, k = kp & 255;
        int r0 = k >> 4, r2 = k & 15;
        int o0 = b * 16 + (c >> 6), o1 = c & 63;   // oo = b*1024+c
        const float* p2 = c2 + (r2 * 64 + o0) * 16;   // stride 1 over r3
        const float* p3 = c3 + o1 * 16 + r0;          // stride 1024 over r3
        float s = 0.f;
#pragma unroll
        for (int r3 = 0; r3 < 16; r3++) s += p2[r3] * p3[r3 * 1024];
        V[id] = f2bf(s);                       // V[kp*1024 + c], c-coalesced
    } else {
        int id = (blk - 12288) * 256 + t;      // [0, 1024*256)
        int k = id & 255, a = id >> 8;
        int r0 = k >> 4, r2 = k & 15;
        int i0 = a >> 5, i1 = a & 31;
        const float* p0 = c0 + (r0 * 32 + i0) * 16;   // stride 1 over r1
        const float* p1 = c1 + i1 * 16 + r2;          // stride 512 over r1
        float s = 0.f;
#pragma unroll
        for (int r1 = 0; r1 < 16; r1++) s += p0[r1] * p1[r1 * 512];
        A2b[id] = f2bf(s);                     // A2b[a*256 + k], k-coalesced
    }
}

// ---------- gemm_z: Z[8192][1024] = Xb @ V^T ; pure-async m97, BM=128 BN=64 ----------
// grid (64,16) = 1024 blocks -> 4 blocks/CU (fixes R4's 2/CU grid limit).
__global__ __launch_bounds__(256) void gemm_z(const ushort_t* __restrict__ Xb,
                                              const ushort_t* __restrict__ V,
                                              ushort_t* __restrict__ Z) {
    __shared__ ushort_t As[128 * 32];
    __shared__ ushort_t Bs[64 * 32];
    const int t = threadIdx.x;
    const int row0 = blockIdx.x * 128;  // s
    const int col0 = blockIdx.y * 64;   // k'
    const int w = t >> 6, l = t & 63;
    const int wm = w >> 1, wn = w & 1;  // waves: 2 (rows) x 2 (cols)
    const int quad = l >> 4, ln = l & 15;

    floatx4 acc[4][2] = {};

    const ushort_t* aSrc = Xb + (size_t)(row0 + (t >> 2)) * 1024 + (t & 3) * 8;
    const ushort_t* bSrc = V  + (size_t)(col0 + (t >> 2)) * 1024 + (t & 3) * 8;
    // NOTE: bSrc row index t>>2 in [0,64) uses all 256 threads for the 64x32 tile.

    for (int kk = 0; kk < 1024; kk += 32) {
        async16(&As[t * 8],        aSrc + kk);
        async16(&As[2048 + t * 8], aSrc + 64 * 1024 + kk);
        async16(&Bs[t * 8],        bSrc + kk);
        __syncthreads();

        short8 a[4], b[2];
#pragma unroll
        for (int ti = 0; ti < 4; ti++)
            a[ti] = *(const short8*)&As[(wm * 64 + ti * 16 + ln) * 32 + quad * 8];
#pragma unroll
        for (int tj = 0; tj < 2; tj++)
            b[tj] = *(const short8*)&Bs[(wn * 32 + tj * 16 + ln) * 32 + quad * 8];
#pragma unroll
        for (int ti = 0; ti < 4; ti++)
#pragma unroll
            for (int tj = 0; tj < 2; tj++)
                acc[ti][tj] = __builtin_amdgcn_mfma_f32_16x16x32_bf16(
                    a[ti], b[tj], acc[ti][tj], 0, 0, 0);
        __syncthreads();
    }

    // D layout: col=lane&15, row=quad*4+reg  [m89]; Z bf16, ld=1024
#pragma unroll
    for (int tj = 0; tj < 2; tj++) {
        const int n = col0 + wn * 32 + tj * 16 + ln;
#pragma unroll
        for (int ti = 0; ti < 4; ti++) {
            const int m = row0 + wm * 64 + ti * 16 + quad * 4;
#pragma unroll
            for (int r = 0; r < 4; r++)
                Z[(size_t)(m + r) * 1024 + n] = f2bf(acc[ti][tj][r]);
        }
    }
}

// ---------- gemm_out: out[s][a*4+b] = sum_k Z[s][b*256+k]*A2b[a][k] + bias ----------
// Four per-b GEMMs (M=8192, N=1024, K=256) folded into grid.y = a_tile*4 + b.
// Pure m97 structure: 128x128 tile, BK=32, 16 MFMA / 2 barriers, 16 KB LDS.
// XCD note: b-partners (same a_tile) are linear-id 64 apart; 64%8==0 -> same
// XCD, adjacent dispatch -> per-XCD L2 merges the 16B-strided stores into
// full lines (joint window 128s x 512j = 256 KB).
__global__ __launch_bounds__(256) void gemm_out(const ushort_t* __restrict__ Z,
                                                const ushort_t* __restrict__ A2b,
                                                const float* __restrict__ bias,
                                                float* __restrict__ out) {
    __shared__ ushort_t As[128 * 32];
    __shared__ ushort_t Bs[128 * 32];
    const int t = threadIdx.x;
    const int row0 = blockIdx.x * 128;        // s
    const int a0 = (blockIdx.y >> 2) * 128;   // a-tile
    const int b  = blockIdx.y & 3;            // which Z k-window / j mod 4
    const int w = t >> 6, l = t & 63;
    const int wm = w >> 1, wn = w & 1;
    const int quad = l >> 4, ln = l & 15;

    floatx4 acc[4][4] = {};

    const ushort_t* aSrc = Z   + (size_t)(row0 + (t >> 2)) * 1024 + b * 256 + (t & 3) * 8;
    const ushort_t* bSrc = A2b + (size_t)(a0   + (t >> 2)) * 256  + (t & 3) * 8;

    for (int kk = 0; kk < 256; kk += 32) {
        async16(&As[t * 8],        aSrc + kk);
        async16(&As[2048 + t * 8], aSrc + 64 * 1024 + kk);
        async16(&Bs[t * 8],        bSrc + kk);
        async16(&Bs[2048 + t * 8], bSrc + 64 * 256 + kk);
        __syncthreads();

        short8 a[4], bb[4];
#pragma unroll
        for (int ti = 0; ti < 4; ti++)
            a[ti] = *(const short8*)&As[(wm * 64 + ti * 16 + ln) * 32 + quad * 8];
#pragma unroll
        for (int tj = 0; tj < 4; tj++)
            bb[tj] = *(const short8*)&Bs[(wn * 64 + tj * 16 + ln) * 32 + quad * 8];
#pragma unroll
        for (int ti = 0; ti < 4; ti++)
#pragma unroll
            for (int tj = 0; tj < 4; tj++)
                acc[ti][tj] = __builtin_amdgcn_mfma_f32_16x16x32_bf16(
                    a[ti], bb[tj], acc[ti][tj], 0, 0, 0);
        __syncthreads();
    }

    // epilogue: C/D col(lane&15) -> a, row(quad*4+reg) -> s; j = a*4 + b
#pragma unroll
    for (int tj = 0; tj < 4; tj++) {
        const int aIdx = a0 + wn * 64 + tj * 16 + ln;
        const int j = aIdx * 4 + b;
        const float bv = bias[j];
#pragma unroll
        for (int ti = 0; ti < 4; ti++) {
            const int m = row0 + wm * 64 + ti * 16 + quad * 4;
            float* o = out + (size_t)m * 4096 + j;
#pragma unroll
            for (int r = 0; r < 4; r++)
                o[(size_t)r * 4096] = acc[ti][tj][r] + bv;
        }
    }
}

extern "C" void kernel_launch(void* const* d_in, const int* in_sizes, int n_in,
                              void* d_out, int out_size, void* d_ws, size_t ws_size,
                              hipStream_t stream) {
    const float* x    = (const float*)d_in[0];   // 8192*1024
    const float* c0   = (const float*)d_in[1];   // 16*32*16
    const float* c1   = (const float*)d_in[2];   // 16*32*16
    const float* c2   = (const float*)d_in[3];   // 16*64*16
    const float* c3   = (const float*)d_in[4];   // 16*64*16
    const float* bias = (const float*)d_in[5];   // 4096
    float* out = (float*)d_out;                  // 8192*4096

    char* ws = (char*)d_ws;
    ushort_t* Xb  = (ushort_t*)ws;                    // 16 MB  bf16 x
    ushort_t* V   = (ushort_t*)(ws + (16u << 20));    //  2 MB  bf16 V[k'][c]
    ushort_t* A2b = (ushort_t*)(ws + (18u << 20));    // 0.5 MB bf16 A2b[a][k]
    ushort_t* Zb  = (ushort_t*)(ws + (20u << 20));    // 16 MB  bf16 Z[s][k']

    hipLaunchKernelGGL(prep_all, dim3(13312), dim3(256), 0, stream,
                       x, c0, c1, c2, c3, Xb, V, A2b);
    hipLaunchKernelGGL(gemm_z,   dim3(64, 16), dim3(256), 0, stream, Xb, V, Zb);
    hipLaunchKernelGGL(gemm_out, dim3(64, 32), dim3(256), 0, stream, Zb, A2b, bias, out);
}

// Round 6
// 255.258 us; speedup vs baseline: 1.1255x; 1.1255x over previous
//
#include <hip/hip_runtime.h>
#include <hip/hip_bf16.h>
#include <stdint.h>

typedef unsigned short ushort_t;
typedef __attribute__((ext_vector_type(8))) short short8;
typedef __attribute__((ext_vector_type(4))) float floatx4;

// ---------- helpers ----------
__device__ __forceinline__ ushort_t f2bf(float f) {
    union { float f; unsigned u; } v; v.f = f;
    unsigned r = v.u + 0x7fffu + ((v.u >> 16) & 1u);   // RTNE
    return (ushort_t)(r >> 16);
}

__device__ __forceinline__ void async16(ushort_t* lds, const ushort_t* g) {
    __builtin_amdgcn_global_load_lds(
        (const __attribute__((address_space(1))) unsigned int*)g,
        (__attribute__((address_space(3))) unsigned int*)lds, 16, 0, 0);
}

// ================= the reshape trap (load-bearing comment) =================
// Reference: w3 axes (i0,i1,o0,o1), flat = ii*4096+oo, then reshape(4096,1024):
//   W_mat[r][c]: ii = r>>2, oo = (r&3)*1024 + c   (c is x's column!)
// out[s][j] = sum_k A2[j>>2][k] * Z[s][(j&3)*256+k]     (A2's k does NOT
//   Z[s][b*256+k] = sum_c x[s][c] * B2[k][b*1024+c]      depend on b!)
// A2[ii][k]=sum_r1 c0*c1 (k=r0*16+r2);  B2[k][oo]=sum_r3 c2*c3.
// Per-b output blocks are FORBIDDEN: they force 16B-strided stores
// (R5: WRITE_SIZE 220 MB, 100 us). b must stay in-register.
// ===========================================================================

// ---------- prep: cvt x->bf16; V[k'][c]; A2b[a][k] (all bf16) ----------
// blocks [0,8192): cvt; [8192,12288): V (1024x1024); [12288,13312): A2b (1024x256)
__global__ __launch_bounds__(256) void prep_all(const float* __restrict__ x,
                                                const float* __restrict__ c0,
                                                const float* __restrict__ c1,
                                                const float* __restrict__ c2,
                                                const float* __restrict__ c3,
                                                ushort_t* __restrict__ Xb,
                                                ushort_t* __restrict__ V,
                                                ushort_t* __restrict__ A2b) {
    const int blk = blockIdx.x, t = threadIdx.x;
    if (blk < 8192) {
        int i = blk * 256 + t;                 // float4 index, n4 = 2M
        float4 v = ((const float4*)x)[i];
        ushort4 r;
        r.x = f2bf(v.x); r.y = f2bf(v.y); r.z = f2bf(v.z); r.w = f2bf(v.w);
        ((ushort4*)Xb)[i] = r;
    } else if (blk < 12288) {
        int id = (blk - 8192) * 256 + t;       // [0, 1024*1024)
        int c = id & 1023, kp = id >> 10;      // kp = b*256+k
        int b = kp >> 8, k = kp & 255;
        int r0 = k >> 4, r2 = k & 15;
        int o0 = b * 16 + (c >> 6), o1 = c & 63;   // oo = b*1024+c
        const float* p2 = c2 + (r2 * 64 + o0) * 16;   // stride 1 over r3
        const float* p3 = c3 + o1 * 16 + r0;          // stride 1024 over r3
        float s = 0.f;
#pragma unroll
        for (int r3 = 0; r3 < 16; r3++) s += p2[r3] * p3[r3 * 1024];
        V[id] = f2bf(s);                       // V[kp*1024 + c], c-coalesced
    } else {
        int id = (blk - 12288) * 256 + t;      // [0, 1024*256)
        int k = id & 255, a = id >> 8;
        int r0 = k >> 4, r2 = k & 15;
        int i0 = a >> 5, i1 = a & 31;
        const float* p0 = c0 + (r0 * 32 + i0) * 16;   // stride 1 over r1
        const float* p1 = c1 + i1 * 16 + r2;          // stride 512 over r1
        float s = 0.f;
#pragma unroll
        for (int r1 = 0; r1 < 16; r1++) s += p0[r1] * p1[r1 * 512];
        A2b[id] = f2bf(s);                     // A2b[a*256 + k], k-coalesced
    }
}

// ---------- gemm_z: Z[8192][1024] = Xb @ V^T ; pure m97 128x128/BK=32 ----------
// grid (64,8) = 512 blocks. 16 MFMA per barrier-pair, all-async staging.
__global__ __launch_bounds__(256) void gemm_z(const ushort_t* __restrict__ Xb,
                                              const ushort_t* __restrict__ V,
                                              ushort_t* __restrict__ Z) {
    __shared__ ushort_t As[128 * 32];
    __shared__ ushort_t Bs[128 * 32];
    const int t = threadIdx.x;
    const int row0 = blockIdx.x * 128;  // s
    const int col0 = blockIdx.y * 128;  // k'
    const int w = t >> 6, l = t & 63;
    const int wm = w >> 1, wn = w & 1;
    const int quad = l >> 4, ln = l & 15;

    floatx4 acc[4][4] = {};

    const ushort_t* aSrc = Xb + (size_t)(row0 + (t >> 2)) * 1024 + (t & 3) * 8;
    const ushort_t* bSrc = V  + (size_t)(col0 + (t >> 2)) * 1024 + (t & 3) * 8;

    for (int kk = 0; kk < 1024; kk += 32) {
        async16(&As[t * 8],        aSrc + kk);
        async16(&As[2048 + t * 8], aSrc + 64 * 1024 + kk);
        async16(&Bs[t * 8],        bSrc + kk);
        async16(&Bs[2048 + t * 8], bSrc + 64 * 1024 + kk);
        __syncthreads();

        short8 a[4], b[4];
#pragma unroll
        for (int ti = 0; ti < 4; ti++)
            a[ti] = *(const short8*)&As[(wm * 64 + ti * 16 + ln) * 32 + quad * 8];
#pragma unroll
        for (int tj = 0; tj < 4; tj++)
            b[tj] = *(const short8*)&Bs[(wn * 64 + tj * 16 + ln) * 32 + quad * 8];
#pragma unroll
        for (int ti = 0; ti < 4; ti++)
#pragma unroll
            for (int tj = 0; tj < 4; tj++)
                acc[ti][tj] = __builtin_amdgcn_mfma_f32_16x16x32_bf16(
                    a[ti], b[tj], acc[ti][tj], 0, 0, 0);
        __syncthreads();
    }

    // D layout: col=lane&15, row=quad*4+reg  [m89]; Z bf16, ld=1024
#pragma unroll
    for (int tj = 0; tj < 4; tj++) {
        const int n = col0 + wn * 64 + tj * 16 + ln;
#pragma unroll
        for (int ti = 0; ti < 4; ti++) {
            const int m = row0 + wm * 64 + ti * 16 + quad * 4;
#pragma unroll
            for (int r = 0; r < 4; r++)
                Z[(size_t)(m + r) * 1024 + n] = f2bf(acc[ti][tj][r]);
        }
    }
}

// ---------- gemm_out: out[s][a*4+b] = sum_k Z[s][b*256+k]*A2b[a][k] + bias ----------
// Block = 128 s x 256 j (64 a x 4 b, b in-register). A2 slice LDS-resident
// (padded ld=264 -> 2-way banks, free). Per kk: stage 4 Z windows (32 KB),
// 32 MFMA per barrier-pair (ti4 x tj2 x b4), bb shared across b.
// Epilogue: recombine b=0..3 -> coalesced float4 stores. Grid (64,16).
__global__ __launch_bounds__(256) void gemm_out(const ushort_t* __restrict__ Z,
                                                const ushort_t* __restrict__ A2b,
                                                const float* __restrict__ bias,
                                                float* __restrict__ out) {
    __shared__ ushort_t Zs[4 * 128 * 32];   // 4 b-windows, m97 [row][k] layout
    __shared__ ushort_t A2s[64 * 264];      // 64 a x 256 k, +8 pad
    const int t = threadIdx.x;
    const int row0 = blockIdx.x * 128;      // s
    const int a0 = blockIdx.y * 64;         // a-tile (j = [a0*4, a0*4+256))
    const int w = t >> 6, l = t & 63;
    const int wm = w >> 1, wn = w & 1;
    const int quad = l >> 4, ln = l & 15;

    floatx4 acc[4][2][4] = {};   // [ti(s)][tj(a)][b]

    // stage A2 slice (64 x 256 = 32 KB) once; VGPR path so padding is allowed
#pragma unroll
    for (int q = 0; q < 8; q++) {
        int g = q * 2048 + t * 8;           // flat element in the 64x256 block
        int r = g >> 8, cidx = g & 255;
        short8 v = *(const short8*)(A2b + (size_t)(a0 + r) * 256 + cidx);
        *(short8*)&A2s[r * 264 + cidx] = v;
    }

    const ushort_t* zSrc = Z + (size_t)(row0 + (t >> 2)) * 1024 + (t & 3) * 8;

    for (int kk = 0; kk < 256; kk += 32) {
#pragma unroll
        for (int b = 0; b < 4; b++) {
            async16(&Zs[b * 4096 + t * 8],        zSrc + b * 256 + kk);
            async16(&Zs[b * 4096 + 2048 + t * 8], zSrc + 64 * 1024 + b * 256 + kk);
        }
        __syncthreads();   // first iter also covers the A2s VGPR-path writes

        short8 bb[2];
#pragma unroll
        for (int tj = 0; tj < 2; tj++)
            bb[tj] = *(const short8*)&A2s[(wn * 32 + tj * 16 + ln) * 264 + kk + quad * 8];
#pragma unroll
        for (int b = 0; b < 4; b++) {
#pragma unroll
            for (int ti = 0; ti < 4; ti++) {
                short8 av = *(const short8*)&Zs[b * 4096 + (wm * 64 + ti * 16 + ln) * 32 + quad * 8];
#pragma unroll
                for (int tj = 0; tj < 2; tj++)
                    acc[ti][tj][b] = __builtin_amdgcn_mfma_f32_16x16x32_bf16(
                        av, bb[tj], acc[ti][tj][b], 0, 0, 0);
            }
        }
        __syncthreads();
    }

    // epilogue: C/D col(lane&15) -> a, row(quad*4+reg) -> s; j = a*4 + b.
    // Lanes ln=0..15 -> float4 addresses 16 B apart = 256 B contiguous.
#pragma unroll
    for (int tj = 0; tj < 2; tj++) {
        const int aIdx = a0 + wn * 32 + tj * 16 + ln;
        const float4 bv = *(const float4*)(bias + aIdx * 4);
#pragma unroll
        for (int ti = 0; ti < 4; ti++) {
#pragma unroll
            for (int r = 0; r < 4; r++) {
                const int s = row0 + wm * 64 + ti * 16 + quad * 4 + r;
                float4 o;
                o.x = acc[ti][tj][0][r] + bv.x;
                o.y = acc[ti][tj][1][r] + bv.y;
                o.z = acc[ti][tj][2][r] + bv.z;
                o.w = acc[ti][tj][3][r] + bv.w;
                *(float4*)(out + (size_t)s * 4096 + aIdx * 4) = o;
            }
        }
    }
}

extern "C" void kernel_launch(void* const* d_in, const int* in_sizes, int n_in,
                              void* d_out, int out_size, void* d_ws, size_t ws_size,
                              hipStream_t stream) {
    const float* x    = (const float*)d_in[0];   // 8192*1024
    const float* c0   = (const float*)d_in[1];   // 16*32*16
    const float* c1   = (const float*)d_in[2];   // 16*32*16
    const float* c2   = (const float*)d_in[3];   // 16*64*16
    const float* c3   = (const float*)d_in[4];   // 16*64*16
    const float* bias = (const float*)d_in[5];   // 4096
    float* out = (float*)d_out;                  // 8192*4096

    char* ws = (char*)d_ws;
    ushort_t* Xb  = (ushort_t*)ws;                    // 16 MB  bf16 x
    ushort_t* V   = (ushort_t*)(ws + (16u << 20));    //  2 MB  bf16 V[k'][c]
    ushort_t* A2b = (ushort_t*)(ws + (18u << 20));    // 0.5 MB bf16 A2b[a][k]
    ushort_t* Zb  = (ushort_t*)(ws + (20u << 20));    // 16 MB  bf16 Z[s][k']

    hipLaunchKernelGGL(prep_all, dim3(13312), dim3(256), 0, stream,
                       x, c0, c1, c2, c3, Xb, V, A2b);
    hipLaunchKernelGGL(gemm_z,   dim3(64, 8),  dim3(256), 0, stream, Xb, V, Zb);
    hipLaunchKernelGGL(gemm_out, dim3(64, 16), dim3(256), 0, stream, Zb, A2b, bias, out);
}